// Round 6
// baseline (804.588 us; speedup 1.0000x reference)
//
#include <hip/hip_runtime.h>
#include <stdint.h>
#include <stddef.h>

#define BATCH 64
#define NN    1024
#define DD    64   // DIN == DOUT == 64
#define CTRS  32   // ints per counter slot (128 B) - one cache line per batch counter

typedef _Float16 h8 __attribute__((ext_vector_type(8)));
typedef _Float16 h4 __attribute__((ext_vector_type(4)));
typedef float    f32x4 __attribute__((ext_vector_type(4)));

// XOR-swizzled granule slot for 128-row tiles (k_xw): [rows][8 granules of 16B].
__device__ __forceinline__ int swz(int row, int gran) {
    return (row << 3) + (gran ^ (row & 7));
}

// ---------------- K0: weight -> WT (transposed fp16) + weight copy + ctr zero ----------
__global__ __launch_bounds__(256) void k_wt(const float* __restrict__ w,
                                            _Float16* __restrict__ wt,
                                            float* __restrict__ ow,
                                            int* __restrict__ ctr) {
#pragma unroll
    for (int z = 0; z < 8; ++z) ctr[threadIdx.x + (z << 8)] = 0;   // 64 * CTRS ints
#pragma unroll
    for (int it = 0; it < 4; ++it) {
        const int idx = threadIdx.x + (it << 8);   // float4 index 0..1023
        const int k = idx >> 4, d4 = idx & 15;
        const float4 v = ((const float4*)w)[idx];
        wt[(d4 * 4 + 0) * DD + k] = (_Float16)v.x;
        wt[(d4 * 4 + 1) * DD + k] = (_Float16)v.y;
        wt[(d4 * 4 + 2) * DD + k] = (_Float16)v.z;
        wt[(d4 * 4 + 3) * DD + k] = (_Float16)v.w;
        ((float4*)ow)[idx] = v;                     // tuple output #1: weight passthrough
    }
}

// ---------------- K1: z^T[b][d][j] = (att @ W)[j][d], fp16, UNscaled -------------------
__global__ __launch_bounds__(256) void k_xw(const float* __restrict__ att,
                                            const _Float16* __restrict__ wt,
                                            _Float16* __restrict__ zT) {
    __shared__ __align__(16) _Float16 attS[128 * 64];
    __shared__ __align__(16) _Float16 wtS[64 * 64];
    const int t = threadIdx.x;
    const int bb = blockIdx.y;
    const int j0 = blockIdx.x * 128;

#pragma unroll
    for (int it = 0; it < 4; ++it) {
        const int g = t + (it << 8);
        const int r = g >> 3, c = g & 7;
        const float4* p = (const float4*)(att + (size_t)(bb * NN + j0 + r) * DD + (c << 3));
        const float4 v0 = p[0], v1 = p[1];
        h8 o;
        o[0] = (_Float16)v0.x; o[1] = (_Float16)v0.y; o[2] = (_Float16)v0.z; o[3] = (_Float16)v0.w;
        o[4] = (_Float16)v1.x; o[5] = (_Float16)v1.y; o[6] = (_Float16)v1.z; o[7] = (_Float16)v1.w;
        *(h8*)&attS[swz(r, c) * 8] = o;
    }
#pragma unroll
    for (int it = 0; it < 2; ++it) {
        const int g = t + (it << 8);
        const int r = g >> 3, c = g & 7;
        const h8 v = *(const h8*)(wt + r * DD + (c << 3));
        *(h8*)&wtS[swz(r, c) * 8] = v;
    }
    __syncthreads();

    const int w = t >> 6, lane = t & 63;
    const int lr = lane & 15, lg = lane >> 4;
    const f32x4 zero = {0.f, 0.f, 0.f, 0.f};
    f32x4 acc[2][4];
#pragma unroll
    for (int mf = 0; mf < 2; ++mf)
#pragma unroll
        for (int nf = 0; nf < 4; ++nf) acc[mf][nf] = zero;

#pragma unroll
    for (int kk = 0; kk < 2; ++kk) {
        h8 a[2], bfr[4];
#pragma unroll
        for (int mf = 0; mf < 2; ++mf)
            a[mf] = *(const h8*)&attS[swz(w * 32 + mf * 16 + lr, kk * 4 + lg) * 8];
#pragma unroll
        for (int nf = 0; nf < 4; ++nf)
            bfr[nf] = *(const h8*)&wtS[swz(nf * 16 + lr, kk * 4 + lg) * 8];
#pragma unroll
        for (int mf = 0; mf < 2; ++mf)
#pragma unroll
            for (int nf = 0; nf < 4; ++nf)
                acc[mf][nf] = __builtin_amdgcn_mfma_f32_16x16x32_f16(a[mf], bfr[nf], acc[mf][nf], 0, 0, 0);
    }

    // D layout: col(d)=lane&15, row(j)=(lane>>4)*4+reg -> 4 consecutive j -> 8B store.
#pragma unroll
    for (int mf = 0; mf < 2; ++mf) {
        const int jb = j0 + w * 32 + mf * 16 + lg * 4;
#pragma unroll
        for (int nf = 0; nf < 4; ++nf) {
            const int d = nf * 16 + lr;
            h4 o;
            o[0] = (_Float16)acc[mf][nf][0];
            o[1] = (_Float16)acc[mf][nf][1];
            o[2] = (_Float16)acc[mf][nf][2];
            o[3] = (_Float16)acc[mf][nf][3];
            *(h4*)(zT + (size_t)(bb * DD + d) * NN + jb) = o;
        }
    }
}

// ---------------- K2: fused deg + aggregate, adj read ONCE -----------------------------
// 512 persistent blocks (2/CU via 64 KiB LDS). Team = blockIdx&7, rank = blockIdx>>3.
// Block owns rows [rank*16, rank*16+16) of its team's 8 batches. Pipeline per batch q:
//   DEG_LOAD(q+2) (16 NT float4 -> regs, issued EARLY: latency hides under spin+AGG)
//   WAITR(q): RELAXED spin on padded ctr (no invalidate storm) -> sync -> threadfence
//             (the one acquire) -> RESCALE LDS by dinv_j (+dinv_i diag)
//   AGG(q):   MFMA, B straight from global zT (L2-resident), NT out stores
//   DEG_STORE(q+2): rowsum from regs -> dinv (agent store), fp16 -> LDS slot, release.
__global__ __launch_bounds__(256, 2) void k_fused(const float* __restrict__ adj,
                                                  const _Float16* __restrict__ zT,
                                                  float* __restrict__ dinv,
                                                  float* __restrict__ out,
                                                  int* __restrict__ ctr) {
    __shared__ __align__(16) _Float16 A[2][16 * NN];   // 64 KiB total
    const int t = threadIdx.x;
    const int team = blockIdx.x & 7;
    const int rank = blockIdx.x >> 3;
    const int w = t >> 6, lane = t & 63;
    const int b0 = team * 8;
    const int rr = (w << 2) + (lane >> 4);       // this thread's local row 0..15 (DEG)
    const int l16 = lane & 15;
    const int giD = (rank << 4) + rr;            // its global row within batch (DEG)

    f32x4 pv[16];                                 // in-flight adj row chunk (64 VGPRs)

    auto DEG_LOAD = [&](int b) {
        const f32x4* rp = (const f32x4*)(adj + ((size_t)b * NN + giD) * NN);
#pragma unroll
        for (int c = 0; c < 16; ++c)
            pv[c] = __builtin_nontemporal_load(rp + l16 + (c << 4));
    };

    auto DEG_STORE = [&](int b, _Float16* As) {
        float s = 0.f;
#pragma unroll
        for (int c = 0; c < 16; ++c) {
            const f32x4 v = pv[c];
            s += v[0] + v[1] + v[2] + v[3];
            const int f4 = l16 + (c << 4);       // float4 index 0..255
            const int g = f4 >> 1;               // 16B granule 0..127
            h4 o;
            o[0] = (_Float16)v[0]; o[1] = (_Float16)v[1];
            o[2] = (_Float16)v[2]; o[3] = (_Float16)v[3];
            *(h4*)(As + (((rr << 7) + (g ^ rr)) << 3) + ((f4 & 1) << 2)) = o;
        }
#pragma unroll
        for (int off = 1; off < 16; off <<= 1) s += __shfl_xor(s, off);
        if (l16 == 0)
            __hip_atomic_store(dinv + b * NN + giD, 1.f / sqrtf(s),
                               __ATOMIC_RELAXED, __HIP_MEMORY_SCOPE_AGENT);
        __syncthreads();                         // all waves' stores drained
        if (t == 0)
            __hip_atomic_fetch_add(ctr + b * CTRS, 1,
                                   __ATOMIC_RELEASE, __HIP_MEMORY_SCOPE_AGENT);
    };

    auto WAITR = [&](int b, _Float16* As) {
        if (t == 0) {
            while (__hip_atomic_load(ctr + b * CTRS, __ATOMIC_RELAXED,
                                     __HIP_MEMORY_SCOPE_AGENT) < 64)
                __builtin_amdgcn_s_sleep(8);
        }
        __syncthreads();
        __threadfence();                         // the acquire: fresh dinv below
        // rescale: thread owns row r = t>>4, logical granules (t&15)*8 .. +7
        const int r = t >> 4;
        const int gi = (rank << 4) + r;
        const float* db = dinv + b * NN;
        const float dgi = db[gi];
#pragma unroll
        for (int gg = 0; gg < 8; ++gg) {
            const int g = ((t & 15) << 3) + gg;  // 0..127
            _Float16* p = As + (((r << 7) + (g ^ r)) << 3);
            const h8 v = *(const h8*)p;
            const f32x4 d0 = *(const f32x4*)(db + (g << 3));
            const f32x4 d1 = *(const f32x4*)(db + (g << 3) + 4);
            const int eDiag = ((gi >> 3) == g) ? (gi & 7) : -1;
            h8 o;
#pragma unroll
            for (int e = 0; e < 8; ++e) {
                const float dj = (e < 4) ? d0[e & 3] : d1[e & 3];
                float f = (float)v[e] * dj;
                if (e == eDiag) f += dgi;        // self-loop: += dinv_i at j==i
                o[e] = (_Float16)f;
            }
            *(h8*)p = o;
        }
        __syncthreads();
    };

    auto AGG = [&](int b, const _Float16* As) {
        const int lr = lane & 15, lg = lane >> 4;
        const f32x4 zero = {0.f, 0.f, 0.f, 0.f};
        f32x4 acc0 = zero, acc1 = zero;          // 2 chains to break MFMA dep latency
        const _Float16* zb = zT + ((size_t)b * DD + (w << 4) + lr) * NN;
        const _Float16* ar = As + ((lr << 7) << 3);
#pragma unroll 4
        for (int g2 = 0; g2 < 32; g2 += 2) {
            const int gA0 = (g2 << 2) + lg;      // granule = mfma*4 + lg
            const int gA1 = gA0 + 4;
            const h8 a0 = *(const h8*)(ar + ((gA0 ^ lr) << 3));
            const h8 b0 = *(const h8*)(zb + (gA0 << 3));
            acc0 = __builtin_amdgcn_mfma_f32_16x16x32_f16(a0, b0, acc0, 0, 0, 0);
            const h8 a1 = *(const h8*)(ar + ((gA1 ^ lr) << 3));
            const h8 b1 = *(const h8*)(zb + (gA1 << 3));
            acc1 = __builtin_amdgcn_mfma_f32_16x16x32_f16(a1, b1, acc1, 0, 0, 0);
        }
        const f32x4 acc = acc0 + acc1;
        // C layout: col(d)=lane&15, row(i)=(lane>>4)*4+reg
        const int i0 = (rank << 4) + (lg << 2);
        const float* db = dinv + b * NN;
#pragma unroll
        for (int reg = 0; reg < 4; ++reg) {
            const float val = acc[reg] * db[i0 + reg];
            __builtin_nontemporal_store(val, out + ((size_t)b * NN + i0 + reg) * DD + (w << 4) + lr);
        }
    };

    DEG_LOAD(b0 + 0); DEG_STORE(b0 + 0, A[0]);
    DEG_LOAD(b0 + 1); DEG_STORE(b0 + 1, A[1]);
#pragma unroll 1
    for (int q = 0; q < 8; ++q) {
        _Float16* As = A[q & 1];
        if (q < 6) DEG_LOAD(b0 + q + 2);         // in flight across spin+RESCALE+AGG
        WAITR(b0 + q, As);
        AGG(b0 + q, As);
        __syncthreads();                         // AGG's LDS reads done before slot reuse
        if (q < 6) DEG_STORE(b0 + q + 2, As);
    }
}

extern "C" void kernel_launch(void* const* d_in, const int* in_sizes, int n_in,
                              void* d_out, int out_size, void* d_ws, size_t ws_size,
                              hipStream_t stream) {
    const float* adj = (const float*)d_in[0];
    const float* att = (const float*)d_in[1];
    const float* wgt = (const float*)d_in[2];
    float* out = (float*)d_out;
    char* ws = (char*)d_ws;

    size_t off = 0;
    _Float16* zT  = (_Float16*)(ws + off); off += (size_t)BATCH * DD * NN * 2;  // 8 MiB
    float*    dinv = (float*)(ws + off);   off += (size_t)BATCH * NN * 4;       // 256 KiB
    _Float16* wt  = (_Float16*)(ws + off); off += (size_t)DD * DD * 2;          // 8 KiB
    int*      ctr = (int*)(ws + off);                                           // 8 KiB

    k_wt<<<1, 256, 0, stream>>>(wgt, wt, out + (size_t)BATCH * NN * DD, ctr);
    k_xw<<<dim3(NN / 128, BATCH), 256, 0, stream>>>(att, wt, zT);
    k_fused<<<512, 256, 0, stream>>>(adj, zT, dinv, out, ctr);
}

// Round 7
// 216.679 us; speedup vs baseline: 3.7133x; 3.7133x over previous
//
#include <hip/hip_runtime.h>
#include <stdint.h>
#include <stddef.h>

#define BATCH 64
#define NN    1024
#define DD    64   // DIN == DOUT == 64
#define CTRS  32   // ints per counter slot (128 B): one cache line per batch counter

typedef _Float16 h8 __attribute__((ext_vector_type(8)));
typedef _Float16 h4 __attribute__((ext_vector_type(4)));
typedef float    f32x4 __attribute__((ext_vector_type(4)));

// XOR-swizzled granule slot: [rows][8 granules of 16B] tiles.
__device__ __forceinline__ int swz(int row, int gran) {
    return (row << 3) + (gran ^ (row & 7));
}

// ---------------- K0: weight -> WT (transposed fp16) + weight copy + ctr zero ----------
__global__ __launch_bounds__(256) void k_wt(const float* __restrict__ w,
                                            _Float16* __restrict__ wt,
                                            float* __restrict__ ow,
                                            int* __restrict__ ctr) {
#pragma unroll
    for (int z = 0; z < 8; ++z) ctr[threadIdx.x + (z << 8)] = 0;   // 64 * CTRS ints
#pragma unroll
    for (int it = 0; it < 4; ++it) {
        const int idx = threadIdx.x + (it << 8);   // float4 index 0..1023
        const int k = idx >> 4, d4 = idx & 15;
        const float4 v = ((const float4*)w)[idx];
        wt[(d4 * 4 + 0) * DD + k] = (_Float16)v.x;
        wt[(d4 * 4 + 1) * DD + k] = (_Float16)v.y;
        wt[(d4 * 4 + 2) * DD + k] = (_Float16)v.z;
        wt[(d4 * 4 + 3) * DD + k] = (_Float16)v.w;
        ((float4*)ow)[idx] = v;                     // tuple output #1: weight passthrough
    }
}

// ---------------- K1: z^T[b][d][j] = (att @ W)[j][d], fp16, UNscaled -------------------
__global__ __launch_bounds__(256) void k_xw(const float* __restrict__ att,
                                            const _Float16* __restrict__ wt,
                                            _Float16* __restrict__ zT) {
    __shared__ __align__(16) _Float16 attS[128 * 64];
    __shared__ __align__(16) _Float16 wtS[64 * 64];
    const int t = threadIdx.x;
    const int bb = blockIdx.y;
    const int j0 = blockIdx.x * 128;

#pragma unroll
    for (int it = 0; it < 4; ++it) {
        const int g = t + (it << 8);
        const int r = g >> 3, c = g & 7;
        const float4* p = (const float4*)(att + (size_t)(bb * NN + j0 + r) * DD + (c << 3));
        const float4 v0 = p[0], v1 = p[1];
        h8 o;
        o[0] = (_Float16)v0.x; o[1] = (_Float16)v0.y; o[2] = (_Float16)v0.z; o[3] = (_Float16)v0.w;
        o[4] = (_Float16)v1.x; o[5] = (_Float16)v1.y; o[6] = (_Float16)v1.z; o[7] = (_Float16)v1.w;
        *(h8*)&attS[swz(r, c) * 8] = o;
    }
#pragma unroll
    for (int it = 0; it < 2; ++it) {
        const int g = t + (it << 8);
        const int r = g >> 3, c = g & 7;
        const h8 v = *(const h8*)(wt + r * DD + (c << 3));
        *(h8*)&wtS[swz(r, c) * 8] = v;
    }
    __syncthreads();

    const int w = t >> 6, lane = t & 63;
    const int lr = lane & 15, lg = lane >> 4;
    const f32x4 zero = {0.f, 0.f, 0.f, 0.f};
    f32x4 acc[2][4];
#pragma unroll
    for (int mf = 0; mf < 2; ++mf)
#pragma unroll
        for (int nf = 0; nf < 4; ++nf) acc[mf][nf] = zero;

#pragma unroll
    for (int kk = 0; kk < 2; ++kk) {
        h8 a[2], bfr[4];
#pragma unroll
        for (int mf = 0; mf < 2; ++mf)
            a[mf] = *(const h8*)&attS[swz(w * 32 + mf * 16 + lr, kk * 4 + lg) * 8];
#pragma unroll
        for (int nf = 0; nf < 4; ++nf)
            bfr[nf] = *(const h8*)&wtS[swz(nf * 16 + lr, kk * 4 + lg) * 8];
#pragma unroll
        for (int mf = 0; mf < 2; ++mf)
#pragma unroll
            for (int nf = 0; nf < 4; ++nf)
                acc[mf][nf] = __builtin_amdgcn_mfma_f32_16x16x32_f16(a[mf], bfr[nf], acc[mf][nf], 0, 0, 0);
    }

    // D layout: col(d)=lane&15, row(j)=(lane>>4)*4+reg -> 4 consecutive j -> 8B store.
#pragma unroll
    for (int mf = 0; mf < 2; ++mf) {
        const int jb = j0 + w * 32 + mf * 16 + lg * 4;
#pragma unroll
        for (int nf = 0; nf < 4; ++nf) {
            const int d = nf * 16 + lr;
            h4 o;
            o[0] = (_Float16)acc[mf][nf][0];
            o[1] = (_Float16)acc[mf][nf][1];
            o[2] = (_Float16)acc[mf][nf][2];
            o[3] = (_Float16)acc[mf][nf][3];
            *(h4*)(zT + (size_t)(bb * DD + d) * NN + jb) = o;
        }
    }
}

// ---------------- K2: deg (own rows, cached) + 16-block barrier + aggregate ------------
// Grid 1024 = 4 blocks/CU (16 KiB LDS), all co-resident. Block x: batch bb=x&63,
// rows [i0, i0+64) with i0=(x>>6)*64. Phase 1 streams its OWN 64 adj rows with
// NORMAL cached loads (row sums -> dinv), so phase 2's re-read of the same rows is
// served by L2/L3, not HBM. Barrier = 16 arrivals on a padded per-batch counter
// (blocks of one batch share an XCD under round-robin: stride 64 = 0 mod 8).
// Phase 2 = round-3 proven k_agg body (fp32 staging, dinv_j fold, diag fixup).
__global__ __launch_bounds__(256, 4) void k_degagg(const float* __restrict__ adj,
                                                   const _Float16* __restrict__ zT,
                                                   float* __restrict__ dinv,
                                                   float* __restrict__ out,
                                                   int* __restrict__ ctr) {
    __shared__ __align__(16) _Float16 adjS[64 * 64];
    __shared__ __align__(16) _Float16 zS[64 * 64];
    const int t = threadIdx.x;
    const int x = blockIdx.x;
    const int bb = x & 63;
    const int i0 = (x >> 6) << 6;
    const int w = t >> 6, lane = t & 63;

    // ---- phase 1: degrees of rows i0..i0+63 (wave w: 16 rows, lane-parallel) ----
#pragma unroll 1
    for (int rr = 0; rr < 16; ++rr) {
        const int gi = i0 + (w << 4) + rr;
        const float* rp = adj + ((size_t)bb * NN + gi) * NN;
        float s = 0.f;
#pragma unroll
        for (int k = 0; k < 4; ++k) {
            const float4 v = ((const float4*)rp)[lane + (k << 6)];
            s += v.x + v.y + v.z + v.w;
        }
#pragma unroll
        for (int off = 32; off; off >>= 1) s += __shfl_xor(s, off);
        if (lane == 0)
            __hip_atomic_store(dinv + bb * NN + gi, 1.f / sqrtf(s),
                               __ATOMIC_RELAXED, __HIP_MEMORY_SCOPE_AGENT);
    }
    __syncthreads();                                 // all stores drained
    if (t == 0)
        __hip_atomic_fetch_add(ctr + bb * CTRS, 1, __ATOMIC_RELEASE, __HIP_MEMORY_SCOPE_AGENT);

    // ---- wait for the batch's 16 blocks ----
    if (t == 0) {
        while (__hip_atomic_load(ctr + bb * CTRS, __ATOMIC_RELAXED,
                                 __HIP_MEMORY_SCOPE_AGENT) < 16)
            __builtin_amdgcn_s_sleep(8);
    }
    __syncthreads();
    __threadfence();                                 // acquire: fresh dinv below

    // ---- phase 2: aggregate (round-3 body; adj re-read is L2/L3-resident) ----
    const int lr = lane & 15, lg = lane >> 4;
    const float* dvB = dinv + bb * NN;
    const int ktDiag = i0 >> 6;

    const int r0 = t >> 3, c0 = t & 7;
    const int r1 = (t + 256) >> 3, c1 = t & 7;

    float4 pa[2][2];
    float4 pd[2][2];
    h8     pz[2];

    auto loadT = [&](int kt) {
        const int gj0 = kt * 64 + (c0 << 3);
        const float4* p0 = (const float4*)(adj + (size_t)(bb * NN + i0 + r0) * NN + gj0);
        pa[0][0] = p0[0]; pa[0][1] = p0[1];
        pd[0][0] = *(const float4*)(dvB + gj0);
        pd[0][1] = *(const float4*)(dvB + gj0 + 4);
        pz[0] = *(const h8*)(zT + (size_t)(bb * DD + r0) * NN + gj0);
        const int gj1 = kt * 64 + (c1 << 3);
        const float4* p1 = (const float4*)(adj + (size_t)(bb * NN + i0 + r1) * NN + gj1);
        pa[1][0] = p1[0]; pa[1][1] = p1[1];
        pd[1][0] = *(const float4*)(dvB + gj1);
        pd[1][1] = *(const float4*)(dvB + gj1 + 4);
        pz[1] = *(const h8*)(zT + (size_t)(bb * DD + r1) * NN + gj1);
    };
    auto writeT = [&]() {
#pragma unroll
        for (int it = 0; it < 2; ++it) {
            const int r = it ? r1 : r0, c = it ? c1 : c0;
            h8 o;
            o[0] = (_Float16)(pa[it][0].x * pd[it][0].x);
            o[1] = (_Float16)(pa[it][0].y * pd[it][0].y);
            o[2] = (_Float16)(pa[it][0].z * pd[it][0].z);
            o[3] = (_Float16)(pa[it][0].w * pd[it][0].w);
            o[4] = (_Float16)(pa[it][1].x * pd[it][1].x);
            o[5] = (_Float16)(pa[it][1].y * pd[it][1].y);
            o[6] = (_Float16)(pa[it][1].z * pd[it][1].z);
            o[7] = (_Float16)(pa[it][1].w * pd[it][1].w);
            *(h8*)&adjS[swz(r, c) * 8] = o;
            *(h8*)&zS[swz(r, c) * 8] = pz[it];
        }
    };

    const f32x4 zero = {0.f, 0.f, 0.f, 0.f};
    f32x4 acc[4];
#pragma unroll
    for (int nf = 0; nf < 4; ++nf) acc[nf] = zero;

    loadT(0);
#pragma unroll 1
    for (int kt = 0; kt < 16; ++kt) {
        writeT();
        if (kt == ktDiag) {          // uniform condition: diagonal tile fix-up (+I term)
            __syncthreads();
            if (t < 64)
                adjS[swz(t, t >> 3) * 8 + (t & 7)] += (_Float16)dvB[i0 + t];
        }
        __syncthreads();
        if (kt < 15) loadT(kt + 1);  // prefetch overlaps with MFMA below
#pragma unroll
        for (int kk = 0; kk < 2; ++kk) {
            const h8 a = *(const h8*)&adjS[swz(w * 16 + lr, kk * 4 + lg) * 8];
#pragma unroll
            for (int nf = 0; nf < 4; ++nf) {
                const h8 bz = *(const h8*)&zS[swz(nf * 16 + lr, kk * 4 + lg) * 8];
                acc[nf] = __builtin_amdgcn_mfma_f32_16x16x32_f16(a, bz, acc[nf], 0, 0, 0);
            }
        }
        __syncthreads();
    }

    const int ib = i0 + w * 16 + lg * 4;   // 4 consecutive output rows (regs 0..3)
    const float4 dv = *(const float4*)&dvB[ib];
#pragma unroll
    for (int nf = 0; nf < 4; ++nf) {
        const int d = nf * 16 + lr;
        float* op = out + ((size_t)bb * NN + ib) * DD + d;
        __builtin_nontemporal_store(acc[nf][0] * dv.x, op + 0 * DD);
        __builtin_nontemporal_store(acc[nf][1] * dv.y, op + 1 * DD);
        __builtin_nontemporal_store(acc[nf][2] * dv.z, op + 2 * DD);
        __builtin_nontemporal_store(acc[nf][3] * dv.w, op + 3 * DD);
    }
}

extern "C" void kernel_launch(void* const* d_in, const int* in_sizes, int n_in,
                              void* d_out, int out_size, void* d_ws, size_t ws_size,
                              hipStream_t stream) {
    const float* adj = (const float*)d_in[0];
    const float* att = (const float*)d_in[1];
    const float* wgt = (const float*)d_in[2];
    float* out = (float*)d_out;
    char* ws = (char*)d_ws;

    size_t off = 0;
    _Float16* zT  = (_Float16*)(ws + off); off += (size_t)BATCH * DD * NN * 2;  // 8 MiB
    float*    dinv = (float*)(ws + off);   off += (size_t)BATCH * NN * 4;       // 256 KiB
    _Float16* wt  = (_Float16*)(ws + off); off += (size_t)DD * DD * 2;          // 8 KiB
    int*      ctr = (int*)(ws + off);                                           // 8 KiB

    k_wt<<<1, 256, 0, stream>>>(wgt, wt, out + (size_t)BATCH * NN * DD, ctr);
    k_xw<<<dim3(NN / 128, BATCH), 256, 0, stream>>>(att, wt, zT);
    k_degagg<<<BATCH * (NN / 64), 256, 0, stream>>>(adj, zT, dinv, out, ctr);
}